// Round 1
// 3460.846 us; speedup vs baseline: 33.3070x; 33.3070x over previous
//
#include <hip/hip_runtime.h>

typedef unsigned short u16;
typedef unsigned int   u32;
typedef __attribute__((ext_vector_type(4))) float f32x4;
typedef __attribute__((ext_vector_type(8))) short bf16x8;

__device__ __forceinline__ float b2f(u16 h) { return __uint_as_float(((u32)h) << 16); }
__device__ __forceinline__ u16 f2bf(float f) {
  u32 u = __float_as_uint(f);
  return (u16)((u + 0x7fffu + ((u >> 16) & 1u)) >> 16);  // RNE
}
// HW packed f32->bf16 (RNE), 1 inst per 2 elems
__device__ __forceinline__ u32 pack2bf(float a, float b) {
  u32 r;
  asm("v_cvt_pk_bf16_f32 %0, %1, %2" : "=v"(r) : "v"(a), "v"(b));
  return r;
}
__device__ __forceinline__ float sigmoid_f(float x) { return 1.f / (1.f + __expf(-x)); }

__device__ __forceinline__ float ldv(const void* p, size_t i, int f32) {
  return f32 ? ((const float*)p)[i] : b2f(((const u16*)p)[i]);
}
__device__ __forceinline__ void ld8(const void* p, size_t i, int f32, float* o) {
  if (f32) {
    const float* q = (const float*)p + i;
    float4 u = *(const float4*)q, v = *(const float4*)(q + 4);
    o[0] = u.x; o[1] = u.y; o[2] = u.z; o[3] = u.w;
    o[4] = v.x; o[5] = v.y; o[6] = v.z; o[7] = v.w;
  } else {
    uint4 u = *(const uint4*)((const u16*)p + i);
    const u32* w = (const u32*)&u;
#pragma unroll
    for (int t = 0; t < 4; t++) {
      o[2 * t]     = b2f((u16)(w[t] & 0xffffu));
      o[2 * t + 1] = b2f((u16)(w[t] >> 16));
    }
  }
}

// ---------------------------------------------------------------------------
// dtype detector (unchanged): h_0 ~ N(0,1); fp32 halves decoded as bf16 blow
// past 1e6 with overwhelming probability.
// ---------------------------------------------------------------------------
__global__ void detect_kernel(const void* __restrict__ h0, int* __restrict__ flag) {
  if (threadIdx.x == 0) {
    const u16* p = (const u16*)h0;
    float mx = 0.f;
    for (int i = 0; i < 256; i++) mx = fmaxf(mx, fabsf(b2f(p[i])));
    flag[0] = (mx > 1.0e6f) ? 1 : 0;
  }
}

// ---------------------------------------------------------------------------
// Stage an (nrows x 64) tile into swizzled bf16 LDS.
// src row-major, leading dim ld; rows optionally indirected through ridx
// (emb gather). f32 sources are converted via v_cvt_pk_bf16_f32.
// Swizzle: u16 index (r*64+k) ^ ((r&7)<<3) — XOR of the 16B-slot bits; rows
// are 128B apart so this spreads 8 consecutive rows over 8 distinct slots
// (T2 / Guideline 4); ds_read_b128 fragment reads become conflict-free.
// ---------------------------------------------------------------------------
__device__ __forceinline__ void stage_tile(
    u16* __restrict__ dst, const void* __restrict__ src, const int* __restrict__ ridx,
    int row0, int col0, size_t ld, int f32, int nrows, int tid)
{
  const int total = nrows << 6;
  for (int base = tid << 3; base < total; base += 2048) {
    const int r = base >> 6;
    const int k = base & 63;
    const size_t gr = ridx ? (size_t)ridx[row0 + r] : (size_t)(row0 + r);
    const size_t g = gr * ld + (size_t)(col0 + k);
    uint4 o;
    if (f32) {
      const float* q = (const float*)src + g;
      float4 u = *(const float4*)q;
      float4 v = *(const float4*)(q + 4);
      o.x = pack2bf(u.x, u.y); o.y = pack2bf(u.z, u.w);
      o.z = pack2bf(v.x, v.y); o.w = pack2bf(v.z, v.w);
    } else {
      o = *(const uint4*)((const u16*)src + g);
    }
    *(uint4*)(dst + (base ^ ((r & 7) << 3))) = o;
  }
}

// Fragment read for mfma_f32_16x16x32_bf16 (A and B symmetric):
// lane l holds row/col (l&15), k = (l>>4)*8 + t. Same XOR as the writer.
__device__ __forceinline__ bf16x8 read_frag(const u16* __restrict__ s, int rb, int kk, int lane) {
  const int r = rb + (lane & 15);
  const int idx = ((r << 6) + (kk << 5) + ((lane >> 4) << 3)) ^ ((r & 7) << 3);
  return *(const bf16x8*)(s + idx);
}

// ---------------------------------------------------------------------------
// m_t = (x @ Wmx^T + bmx) * (h0 @ Wmh^T + bmh), stored bf16 in workspace.
// Tile 128x64, 4 waves (2M x 2N), wave tile 64x32, BK=64.
// ---------------------------------------------------------------------------
__global__ __launch_bounds__(256) void m_mfma(
    const int* __restrict__ inp, const void* __restrict__ emb, const void* __restrict__ h0,
    const void* __restrict__ Wmx, const void* __restrict__ bmx,
    const void* __restrict__ Wmh, const void* __restrict__ bmh,
    u16* __restrict__ M, const int* __restrict__ flag)
{
  const int f32 = *flag;
  const int tid = threadIdx.x;
  const int lane = tid & 63;
  const int w = tid >> 6, wm = w >> 1, wn = w & 1;

  // XCD-aware bijective swizzle (2048 blocks, 2048 % 8 == 0).
  const int bid = blockIdx.x;
  const int swz = ((bid & 7) << 8) | (bid >> 3);
  const int bm0 = (swz & 63) << 7;   // M-block * 128
  const int bn0 = (swz >> 6) << 6;   // N-block * 64

  __shared__ __attribute__((aligned(16))) u16 sA[128 * 64];
  __shared__ __attribute__((aligned(16))) u16 sW[64 * 64];

  f32x4 ax[4][2], ah[4][2];
#pragma unroll
  for (int mi = 0; mi < 4; mi++)
#pragma unroll
    for (int ni = 0; ni < 2; ni++) {
      ax[mi][ni] = (f32x4){0.f, 0.f, 0.f, 0.f};
      ah[mi][ni] = (f32x4){0.f, 0.f, 0.f, 0.f};
    }

  // Phase A: x = emb[inp] (gathered in staging), K = 1024
  for (int kt = 0; kt < 1024; kt += 64) {
    stage_tile(sA, emb, inp, bm0, kt, 1024, f32, 128, tid);
    stage_tile(sW, Wmx, nullptr, bn0, kt, 1024, f32, 64, tid);
    __syncthreads();
#pragma unroll
    for (int kk = 0; kk < 2; kk++) {
      bf16x8 af[4];
#pragma unroll
      for (int mi = 0; mi < 4; mi++) af[mi] = read_frag(sA, wm * 64 + mi * 16, kk, lane);
      const bf16x8 w0 = read_frag(sW, wn * 32, kk, lane);
      const bf16x8 w1 = read_frag(sW, wn * 32 + 16, kk, lane);
#pragma unroll
      for (int mi = 0; mi < 4; mi++) {
        ax[mi][0] = __builtin_amdgcn_mfma_f32_16x16x32_bf16(af[mi], w0, ax[mi][0], 0, 0, 0);
        ax[mi][1] = __builtin_amdgcn_mfma_f32_16x16x32_bf16(af[mi], w1, ax[mi][1], 0, 0, 0);
      }
    }
    __syncthreads();
  }

  // Phase B: h0, K = 2048
  for (int kt = 0; kt < 2048; kt += 64) {
    stage_tile(sA, h0, nullptr, bm0, kt, 2048, f32, 128, tid);
    stage_tile(sW, Wmh, nullptr, bn0, kt, 2048, f32, 64, tid);
    __syncthreads();
#pragma unroll
    for (int kk = 0; kk < 2; kk++) {
      bf16x8 af[4];
#pragma unroll
      for (int mi = 0; mi < 4; mi++) af[mi] = read_frag(sA, wm * 64 + mi * 16, kk, lane);
      const bf16x8 w0 = read_frag(sW, wn * 32, kk, lane);
      const bf16x8 w1 = read_frag(sW, wn * 32 + 16, kk, lane);
#pragma unroll
      for (int mi = 0; mi < 4; mi++) {
        ah[mi][0] = __builtin_amdgcn_mfma_f32_16x16x32_bf16(af[mi], w0, ah[mi][0], 0, 0, 0);
        ah[mi][1] = __builtin_amdgcn_mfma_f32_16x16x32_bf16(af[mi], w1, ah[mi][1], 0, 0, 0);
      }
    }
    __syncthreads();
  }

  // Epilogue: C/D layout col = lane&15, row = (lane>>4)*4 + j (m89-verified).
#pragma unroll
  for (int ni = 0; ni < 2; ni++) {
    const int col = bn0 + wn * 32 + ni * 16 + (lane & 15);
    const float bx = ldv(bmx, col, f32);
    const float bh = ldv(bmh, col, f32);
#pragma unroll
    for (int mi = 0; mi < 4; mi++) {
      const int rowb = bm0 + wm * 64 + mi * 16 + ((lane >> 4) << 2);
#pragma unroll
      for (int j = 0; j < 4; j++) {
        const float v = (ax[mi][ni][j] + bx) * (ah[mi][ni][j] + bh);
        M[(size_t)(rowb + j) * 2048 + col] = f2bf(v);
      }
    }
  }
}

// ---------------------------------------------------------------------------
// All four gates for a 128x64 tile, fused sigmoid/tanh/cx/hx epilogue.
// Shared A-tile staging (x then m_t), 4 weight tiles per K-step,
// 4 accumulator sets (128 VGPRs).
// ---------------------------------------------------------------------------
__global__ __launch_bounds__(256) void gates_mfma(
    const int* __restrict__ inp, const void* __restrict__ emb, const u16* __restrict__ M,
    const void* __restrict__ Wfx, const void* __restrict__ Wix,
    const void* __restrict__ Wox, const void* __restrict__ Wcx,
    const void* __restrict__ Wfm, const void* __restrict__ Wim,
    const void* __restrict__ Wom, const void* __restrict__ Wcm,
    const void* __restrict__ bfx, const void* __restrict__ bfm,
    const void* __restrict__ bix, const void* __restrict__ bim,
    const void* __restrict__ box_, const void* __restrict__ bom,
    const void* __restrict__ bcx, const void* __restrict__ bcm,
    const void* __restrict__ C0, void* __restrict__ dout, const int* __restrict__ flag)
{
  const int f32 = *flag;
  const int tid = threadIdx.x;
  const int lane = tid & 63;
  const int w = tid >> 6, wm = w >> 1, wn = w & 1;

  const int bid = blockIdx.x;
  const int swz = ((bid & 7) << 8) | (bid >> 3);
  const int bm0 = (swz & 63) << 7;
  const int bn0 = (swz >> 6) << 6;

  __shared__ __attribute__((aligned(16))) u16 sA[128 * 64];
  __shared__ __attribute__((aligned(16))) u16 sW[4][64 * 64];

  const void* Wx[4] = {Wfx, Wix, Wox, Wcx};
  const void* Wm[4] = {Wfm, Wim, Wom, Wcm};

  f32x4 acc[4][4][2];  // [gate][mi][ni]
#pragma unroll
  for (int g = 0; g < 4; g++)
#pragma unroll
    for (int mi = 0; mi < 4; mi++)
#pragma unroll
      for (int ni = 0; ni < 2; ni++) acc[g][mi][ni] = (f32x4){0.f, 0.f, 0.f, 0.f};

  // Phase A: x-projections (K = 1024), A rows gathered from emb via inp
  for (int kt = 0; kt < 1024; kt += 64) {
    stage_tile(sA, emb, inp, bm0, kt, 1024, f32, 128, tid);
#pragma unroll
    for (int g = 0; g < 4; g++) stage_tile(sW[g], Wx[g], nullptr, bn0, kt, 1024, f32, 64, tid);
    __syncthreads();
#pragma unroll
    for (int kk = 0; kk < 2; kk++) {
      bf16x8 af[4];
#pragma unroll
      for (int mi = 0; mi < 4; mi++) af[mi] = read_frag(sA, wm * 64 + mi * 16, kk, lane);
#pragma unroll
      for (int g = 0; g < 4; g++) {
        const bf16x8 w0 = read_frag(sW[g], wn * 32, kk, lane);
        const bf16x8 w1 = read_frag(sW[g], wn * 32 + 16, kk, lane);
#pragma unroll
        for (int mi = 0; mi < 4; mi++) {
          acc[g][mi][0] = __builtin_amdgcn_mfma_f32_16x16x32_bf16(af[mi], w0, acc[g][mi][0], 0, 0, 0);
          acc[g][mi][1] = __builtin_amdgcn_mfma_f32_16x16x32_bf16(af[mi], w1, acc[g][mi][1], 0, 0, 0);
        }
      }
    }
    __syncthreads();
  }

  // Phase B: m_t-projections (K = 2048), A = internal bf16 m_t
  for (int kt = 0; kt < 2048; kt += 64) {
    stage_tile(sA, M, nullptr, bm0, kt, 2048, 0, 128, tid);
#pragma unroll
    for (int g = 0; g < 4; g++) stage_tile(sW[g], Wm[g], nullptr, bn0, kt, 2048, f32, 64, tid);
    __syncthreads();
#pragma unroll
    for (int kk = 0; kk < 2; kk++) {
      bf16x8 af[4];
#pragma unroll
      for (int mi = 0; mi < 4; mi++) af[mi] = read_frag(sA, wm * 64 + mi * 16, kk, lane);
#pragma unroll
      for (int g = 0; g < 4; g++) {
        const bf16x8 w0 = read_frag(sW[g], wn * 32, kk, lane);
        const bf16x8 w1 = read_frag(sW[g], wn * 32 + 16, kk, lane);
#pragma unroll
        for (int mi = 0; mi < 4; mi++) {
          acc[g][mi][0] = __builtin_amdgcn_mfma_f32_16x16x32_bf16(af[mi], w0, acc[g][mi][0], 0, 0, 0);
          acc[g][mi][1] = __builtin_amdgcn_mfma_f32_16x16x32_bf16(af[mi], w1, acc[g][mi][1], 0, 0, 0);
        }
      }
    }
    __syncthreads();
  }

  // Fused epilogue: biases -> gates -> cx, hx (all f32 math).
  const void* bxv[4] = {bfx, bix, box_, bcx};
  const void* bmv[4] = {bfm, bim, bom, bcm};
#pragma unroll
  for (int ni = 0; ni < 2; ni++) {
    const int col = bn0 + wn * 32 + ni * 16 + (lane & 15);
    float bs[4];
#pragma unroll
    for (int g = 0; g < 4; g++) bs[g] = ldv(bxv[g], col, f32) + ldv(bmv[g], col, f32);
#pragma unroll
    for (int mi = 0; mi < 4; mi++) {
      const int rowb = bm0 + wm * 64 + mi * 16 + ((lane >> 4) << 2);
#pragma unroll
      for (int j = 0; j < 4; j++) {
        const size_t idx = (size_t)(rowb + j) * 2048 + col;
        const float fg = sigmoid_f(acc[0][mi][ni][j] + bs[0]);
        const float ig = sigmoid_f(acc[1][mi][ni][j] + bs[1]);
        const float og = sigmoid_f(acc[2][mi][ni][j] + bs[2]);
        const float ct = tanhf(acc[3][mi][ni][j] + bs[3]);
        const float c0v = ldv(C0, idx, f32);
        const float cxv = fg * c0v + ig * ct;
        const float hxv = og * tanhf(cxv);
        const size_t eH = (size_t)16384 + idx;              // hx region
        const size_t eC = eH + (size_t)8192 * 2048;         // cx region
        if (f32) { ((float*)dout)[eH] = hxv; ((float*)dout)[eC] = cxv; }
        else     { ((u16*)dout)[eH] = f2bf(hxv); ((u16*)dout)[eC] = f2bf(cxv); }
      }
    }
  }
}

// ---------------------------------------------------------------------------
// out[row][o] = hx[row] . W_dec[o] + b_dec[o]; one wave per row, both o.
// hx read back from d_out (f32 in f32 mode -> exact f32 decoder).
// ---------------------------------------------------------------------------
__global__ __launch_bounds__(256) void decoder_w(
    const void* __restrict__ Wd, const void* __restrict__ bd,
    void* __restrict__ dout, const int* __restrict__ flag)
{
  const int f32 = *flag;
  const int gid = blockIdx.x * 256 + threadIdx.x;
  const int row = gid >> 6;          // 8192 rows, one wave each
  const int lane = gid & 63;
  const size_t hbase = (size_t)16384 + (size_t)row * 2048;
  float a8[8], w8[8];
  float acc0 = 0.f, acc1 = 0.f;
#pragma unroll
  for (int s = 0; s < 4; s++) {
    const size_t k = (size_t)(s * 64 + lane) * 8;
    ld8(dout, hbase + k, f32, a8);
    ld8(Wd, k, f32, w8);
#pragma unroll
    for (int t = 0; t < 8; t++) acc0 = fmaf(a8[t], w8[t], acc0);
    ld8(Wd, (size_t)2048 + k, f32, w8);
#pragma unroll
    for (int t = 0; t < 8; t++) acc1 = fmaf(a8[t], w8[t], acc1);
  }
#pragma unroll
  for (int off = 32; off > 0; off >>= 1) {
    acc0 += __shfl_down(acc0, off);
    acc1 += __shfl_down(acc1, off);
  }
  if (lane == 0) {
    const float v0 = acc0 + ldv(bd, 0, f32);
    const float v1 = acc1 + ldv(bd, 1, f32);
    if (f32) {
      ((float*)dout)[(size_t)row * 2]     = v0;
      ((float*)dout)[(size_t)row * 2 + 1] = v1;
    } else {
      ((u16*)dout)[(size_t)row * 2]     = f2bf(v0);
      ((u16*)dout)[(size_t)row * 2 + 1] = f2bf(v1);
    }
  }
}

extern "C" void kernel_launch(void* const* d_in, const int* in_sizes, int n_in,
                              void* d_out, int out_size, void* d_ws, size_t ws_size,
                              hipStream_t stream)
{
  const int* inp  = (const int*)d_in[0];
  const void* h0  = d_in[1];
  const void* c0  = d_in[2];
  const void* emb = d_in[3];
  const void* Wmx = d_in[4],  *bmx = d_in[5];
  const void* Wmh = d_in[6],  *bmh = d_in[7];
  const void* Wfx = d_in[8],  *bfx = d_in[9];
  const void* Wfm = d_in[10], *bfm = d_in[11];
  const void* Wix = d_in[12], *bix = d_in[13];
  const void* Wim = d_in[14], *bim = d_in[15];
  const void* Wox = d_in[16], *box_ = d_in[17];
  const void* Wom = d_in[18], *bom = d_in[19];
  const void* Wcx = d_in[20], *bcx = d_in[21];
  const void* Wcm = d_in[22], *bcm = d_in[23];
  const void* Wdec = d_in[24], *bdec = d_in[25];

  int* flag = (int*)d_ws;
  u16* Mw = (u16*)((char*)d_ws + 256);  // [8192,2048] bf16 = 32 MB (same ws footprint as before)

  detect_kernel<<<1, 64, 0, stream>>>(h0, flag);
  m_mfma<<<2048, 256, 0, stream>>>(inp, emb, h0, Wmx, bmx, Wmh, bmh, Mw, flag);
  gates_mfma<<<2048, 256, 0, stream>>>(
      inp, emb, Mw, Wfx, Wix, Wox, Wcx, Wfm, Wim, Wom, Wcm,
      bfx, bfm, bix, bim, box_, bom, bcx, bcm, c0, d_out, flag);
  decoder_w<<<2048, 256, 0, stream>>>(Wdec, bdec, d_out, flag);
}